// Round 4
// baseline (2610.010 us; speedup 1.0000x reference)
//
#include <hip/hip_runtime.h>
#include <hip/hip_bf16.h>
#include <cstdint>
#include <cstddef>

__device__ __forceinline__ float rl_f(float v, int lane) {
  return __int_as_float(__builtin_amdgcn_readlane(__float_as_int(v), lane));
}

// ============ xg GEMM: xg[bt][r] = bih[r]+bhh[r] + sum_d x[bt][d]*Wih[r][d]
// Lane = output row r (wave w covers rows 64w..); Wih row pinned in VGPRs;
// x rows are wave-uniform -> scalar (SGPR) loads feed the FMA SGPR operand.
// Stores: lane=r consecutive -> fully coalesced.
template <int D, int G, int BT_TILE>
__global__ __launch_bounds__(G)
void xg_gemm(const float* __restrict__ W, const float* __restrict__ bih,
             const float* __restrict__ bhh, const float* __restrict__ x,
             float* __restrict__ xg) {
  const int r = threadIdx.x;
  float wr[D];
  const float* Wr = W + (size_t)r * D;
#pragma unroll
  for (int d4 = 0; d4 < D / 4; ++d4) {
    float4 q = ((const float4*)Wr)[d4];
    wr[4 * d4 + 0] = q.x; wr[4 * d4 + 1] = q.y;
    wr[4 * d4 + 2] = q.z; wr[4 * d4 + 3] = q.w;
  }
#pragma unroll
  for (int d = 0; d < D; ++d) asm volatile("" : "+v"(wr[d]));  // pin in VGPRs
  const float bias = bih[r] + bhh[r];
  const size_t bt0 = (size_t)blockIdx.x * BT_TILE;
  for (int i = 0; i < BT_TILE; ++i) {
    const size_t bt = bt0 + i;
    const float* xr = x + bt * D;  // wave-uniform address -> s_load
    float a0 = bias, a1 = 0.f, a2 = 0.f, a3 = 0.f;
#pragma unroll
    for (int d = 0; d < D; d += 4) {
      a0 = fmaf(wr[d + 0], xr[d + 0], a0);
      a1 = fmaf(wr[d + 1], xr[d + 1], a1);
      a2 = fmaf(wr[d + 2], xr[d + 2], a2);
      a3 = fmaf(wr[d + 3], xr[d + 3], a3);
    }
    xg[bt * G + r] = (a0 + a1) + (a2 + a3);
  }
}

// ============ Recurrence. Block=256 (4 waves = gate types i,f,g,o), grid=512.
// Lane k<H of wave g owns row r=g*H+k with Whh row pinned in VGPRs.
// h broadcast via v_readlane (h replicated in lanes <H of every wave).
// Cross-wave traffic: only activated gates via padded ping-pong LDS; ONE
// barrier per step. All waves redundantly maintain c/h (identical fp ops).
// IN_MODE: 0 = xg stream [BT,G] (bias already inside), 1 = latent [B,D]
//          folded into bias, 2 = f32 x-seq [B,T,D] (in-loop, fallback)
// OUT_MODE: 0 = f32 seq [B,T,H], 1 = f32 last-h [B,H]
template <int D, int H, int IN_MODE, int OUT_MODE>
__global__ __launch_bounds__(256)
void lstm_rec(const float* __restrict__ Whh, const float* __restrict__ bih,
              const float* __restrict__ bhh, const float* __restrict__ Wih,
              const float* __restrict__ xin, float* __restrict__ outp, int T) {
  constexpr int G4 = 4 * H;
  (void)G4;
  __shared__ float gbuf[2][H * 5 + 5];
  const int tid = threadIdx.x;
  const int g = tid >> 6;    // gate type
  const int k = tid & 63;    // hidden unit / readlane source
  const int b = blockIdx.x;
  const bool act = (k < H);
  const int r = g * H + (act ? k : 0);

  float whh[H];
  {
    const float* Ur = Whh + (size_t)r * H;
#pragma unroll
    for (int j4 = 0; j4 < H / 4; ++j4) {
      float4 q = ((const float4*)Ur)[j4];
      whh[4 * j4 + 0] = q.x; whh[4 * j4 + 1] = q.y;
      whh[4 * j4 + 2] = q.z; whh[4 * j4 + 3] = q.w;
    }
  }
#pragma unroll
  for (int j = 0; j < H; ++j) asm volatile("" : "+v"(whh[j]));  // pin

  float base = 0.f;
  if (IN_MODE != 0 && act) base = bih[r] + bhh[r];

  float wih[(IN_MODE == 2) ? D : 1];
  if (IN_MODE == 2) {
    const float* Wr = Wih + (size_t)r * D;
#pragma unroll
    for (int d4 = 0; d4 < D / 4; ++d4) {
      float4 q = ((const float4*)Wr)[d4];
      wih[4 * d4 + 0] = q.x; wih[4 * d4 + 1] = q.y;
      wih[4 * d4 + 2] = q.z; wih[4 * d4 + 3] = q.w;
    }
#pragma unroll
    for (int d = 0; d < ((IN_MODE == 2) ? D : 1); ++d) asm volatile("" : "+v"(wih[d]));
  }
  if (IN_MODE == 1 && act) {  // fold Wih @ latent into bias (uniform reads)
    const float* Wr = Wih + (size_t)r * D;
    const float* lat = xin + (size_t)b * D;
#pragma unroll
    for (int d = 0; d < D; ++d) base = fmaf(Wr[d], lat[d], base);
  }

  // Branch-free activation constants: sigma for i,f,o; tanh for g (g==2).
  const bool isT = (g == 2);
  const float sA = isT ? -2.88539008f : -1.44269504f;
  const float aA = isT ? 2.f : 1.f;
  const float bA = isT ? -1.f : 0.f;

  float xg_cur = 0.f, xv_cur = 0.f;
  if (IN_MODE == 0 && act) xg_cur = xin[(size_t)b * T * (4 * H) + r];
  if (IN_MODE == 2 && k < D) xv_cur = xin[(size_t)b * T * D + k];

  float cc = 0.f, hreg = 0.f;
  int p = 0;
  for (int t = 0; t < T; ++t) {
    // prefetch next timestep's input (covered by the compute below)
    float xg_nxt = 0.f, xv_nxt = 0.f;
    if (IN_MODE == 0 && act && t + 1 < T)
      xg_nxt = xin[((size_t)b * T + t + 1) * (4 * H) + r];
    if (IN_MODE == 2 && k < D && t + 1 < T)
      xv_nxt = xin[((size_t)b * T + t + 1) * D + k];

    float a0 = (IN_MODE == 0) ? xg_cur : base, a1 = 0.f, a2 = 0.f, a3 = 0.f;
    if (IN_MODE == 2) {
#pragma unroll
      for (int d = 0; d < D; d += 4) {
        a0 = fmaf(wih[d + 0], rl_f(xv_cur, d + 0), a0);
        a1 = fmaf(wih[d + 1], rl_f(xv_cur, d + 1), a1);
        a2 = fmaf(wih[d + 2], rl_f(xv_cur, d + 2), a2);
        a3 = fmaf(wih[d + 3], rl_f(xv_cur, d + 3), a3);
      }
    }
#pragma unroll
    for (int j = 0; j < H; j += 4) {
      a0 = fmaf(whh[j + 0], rl_f(hreg, j + 0), a0);
      a1 = fmaf(whh[j + 1], rl_f(hreg, j + 1), a1);
      a2 = fmaf(whh[j + 2], rl_f(hreg, j + 2), a2);
      a3 = fmaf(whh[j + 3], rl_f(hreg, j + 3), a3);
    }
    const float pre = (a0 + a1) + (a2 + a3);
    const float e = exp2f(sA * pre);
    const float gv = fmaf(aA, __builtin_amdgcn_rcpf(1.f + e), bA);
    if (act) gbuf[p][k * 5 + g] = gv;
    __syncthreads();  // gates visible; ping-pong makes WAR across steps safe

    if (act) {
      const float gi = gbuf[p][k * 5 + 0];
      const float gf = gbuf[p][k * 5 + 1];
      const float gg = gbuf[p][k * 5 + 2];
      const float go = gbuf[p][k * 5 + 3];
      cc = fmaf(gf, cc, gi * gg);
      const float e2 = exp2f(-2.88539008f * cc);
      hreg = go * fmaf(2.f, __builtin_amdgcn_rcpf(1.f + e2), -1.f);
      if (OUT_MODE == 0) {
        if (g == 0) outp[((size_t)b * T + t) * H + k] = hreg;
      } else {
        if (g == 0 && t == T - 1) outp[(size_t)b * H + k] = hreg;
      }
    }
    xg_cur = xg_nxt;
    xv_cur = xv_nxt;
    p ^= 1;
  }
}

extern "C" void kernel_launch(void* const* d_in, const int* in_sizes, int n_in,
                              void* d_out, int out_size, void* d_ws, size_t ws_size,
                              hipStream_t stream) {
  (void)in_sizes; (void)n_in; (void)out_size;
  const float* x = (const float*)d_in[0];
  const float *W[6], *U[6], *Bi[6], *Bh[6];
  for (int l = 0; l < 6; ++l) {
    W[l]  = (const float*)d_in[1 + 4 * l + 0];
    U[l]  = (const float*)d_in[1 + 4 * l + 1];
    Bi[l] = (const float*)d_in[1 + 4 * l + 2];
    Bh[l] = (const float*)d_in[1 + 4 * l + 3];
  }
  float* out = (float*)d_out;
  const int T = 512;
  const size_t BT = (size_t)512 * 512;

  const size_t szA  = BT * 48 * 4;   // 50.3 MB inter-layer seq buf
  const size_t szB  = BT * 32 * 4;   // 33.6 MB
  const size_t szL  = (size_t)512 * 16 * 4;
  char* ws = (char*)d_ws;
  float* A   = (float*)ws;
  float* Bf  = (float*)(ws + szA);
  float* lat = (float*)(ws + szA + szB);
  float* xg  = (float*)(ws + szA + szB + szL);
  const size_t avail = (ws_size > szA + szB + szL) ? ws_size - (szA + szB + szL) : 0;
  auto fits = [&](int G) { return avail >= BT * (size_t)G * 4; };

  dim3 rgrid(512), rblk(256);

  // e1: 64 -> 48
  if (fits(192)) {
    xg_gemm<64, 192, 256><<<dim3(BT / 256), dim3(192), 0, stream>>>(W[0], Bi[0], Bh[0], x, xg);
    lstm_rec<64, 48, 0, 0><<<rgrid, rblk, 0, stream>>>(U[0], Bi[0], Bh[0], W[0], xg, A, T);
  } else {
    lstm_rec<64, 48, 2, 0><<<rgrid, rblk, 0, stream>>>(U[0], Bi[0], Bh[0], W[0], x, A, T);
  }
  // e2: 48 -> 32
  if (fits(128)) {
    xg_gemm<48, 128, 128><<<dim3(BT / 128), dim3(128), 0, stream>>>(W[1], Bi[1], Bh[1], A, xg);
    lstm_rec<48, 32, 0, 0><<<rgrid, rblk, 0, stream>>>(U[1], Bi[1], Bh[1], W[1], xg, Bf, T);
  } else {
    lstm_rec<48, 32, 2, 0><<<rgrid, rblk, 0, stream>>>(U[1], Bi[1], Bh[1], W[1], A, Bf, T);
  }
  // e3: 32 -> 16 (last-h only)
  if (fits(64)) {
    xg_gemm<32, 64, 64><<<dim3(BT / 64), dim3(64), 0, stream>>>(W[2], Bi[2], Bh[2], Bf, xg);
    lstm_rec<32, 16, 0, 1><<<rgrid, rblk, 0, stream>>>(U[2], Bi[2], Bh[2], W[2], xg, lat, T);
  } else {
    lstm_rec<32, 16, 2, 1><<<rgrid, rblk, 0, stream>>>(U[2], Bi[2], Bh[2], W[2], Bf, lat, T);
  }
  // d1: 16 -> 32 (latent input folded into bias)
  lstm_rec<16, 32, 1, 0><<<rgrid, rblk, 0, stream>>>(U[3], Bi[3], Bh[3], W[3], lat, Bf, T);
  // d2: 32 -> 48
  if (fits(192)) {
    xg_gemm<32, 192, 256><<<dim3(BT / 256), dim3(192), 0, stream>>>(W[4], Bi[4], Bh[4], Bf, xg);
    lstm_rec<32, 48, 0, 0><<<rgrid, rblk, 0, stream>>>(U[4], Bi[4], Bh[4], W[4], xg, A, T);
  } else {
    lstm_rec<32, 48, 2, 0><<<rgrid, rblk, 0, stream>>>(U[4], Bi[4], Bh[4], W[4], Bf, A, T);
  }
  // d3: 48 -> 64
  if (fits(256)) {
    xg_gemm<48, 256, 256><<<dim3(BT / 256), dim3(256), 0, stream>>>(W[5], Bi[5], Bh[5], A, xg);
    lstm_rec<48, 64, 0, 0><<<rgrid, rblk, 0, stream>>>(U[5], Bi[5], Bh[5], W[5], xg, out, T);
  } else {
    lstm_rec<48, 64, 2, 0><<<rgrid, rblk, 0, stream>>>(U[5], Bi[5], Bh[5], W[5], A, out, T);
  }
}

// Round 5
// 1767.105 us; speedup vs baseline: 1.4770x; 1.4770x over previous
//
#include <hip/hip_runtime.h>
#include <hip/hip_bf16.h>
#include <cstdint>
#include <cstddef>

typedef _Float16 half_t;
typedef decltype(__builtin_amdgcn_cvt_pkrtz(0.f, 0.f)) h2;  // v2f16

__device__ __forceinline__ h2 pk2(float a, float b) { return __builtin_amdgcn_cvt_pkrtz(a, b); }
__device__ __forceinline__ float fdot2f(h2 a, h2 b, float c) { return __builtin_amdgcn_fdot2(a, b, c, false); }
__device__ __forceinline__ h2 u2h(uint32_t u) { union { uint32_t u; h2 h; } v; v.u = u; return v.h; }

// Intra-wave LDS handoff: waits for this wave's outstanding LDS ops.
#define WAVE_SYNC() asm volatile("s_waitcnt lgkmcnt(0)" ::: "memory")

// Load one gate-row r: Wih[r][:], Whh[r][:] as f16 pairs, bias, activation
// constants (sigma for gates i,f,o; tanh-as-2*sigma(2x)-1 for gate g), and the
// transposed gate-scratch index GOFF + u*4 + g.
template <int D, int H>
__device__ __forceinline__ void load_one(int r, const float* Wih, const float* Whh,
                                         const float* bi, const float* bh, h2* wrow,
                                         float& bias, float& sA, float& aA, float& bB,
                                         int& gidx, int GOFF) {
  const float* wi = Wih + (size_t)r * D;
#pragma unroll
  for (int p = 0; p < D / 2; ++p) wrow[p] = pk2(wi[2 * p], wi[2 * p + 1]);
  const float* wh = Whh + (size_t)r * H;
#pragma unroll
  for (int p = 0; p < H / 2; ++p) wrow[D / 2 + p] = pk2(wh[2 * p], wh[2 * p + 1]);
  bias = bi[r] + bh[r];
  const int g = r / H;
  const bool isT = (g == 2);
  sA = isT ? -2.88539008f : -1.44269504f;
  aA = isT ? 2.f : 1.f;
  bB = isT ? -1.f : 0.f;
  gidx = GOFF + (r % H) * 4 + g;
}

// Rows r = 64*j + lane (whole layer in one wave; 4H == 64*R).
template <int D, int H, int R>
__device__ __forceinline__ void load_rows(int lane, const float* Wih, const float* Whh,
                                          const float* bi, const float* bh, h2* w,
                                          float* bias, float* sA, float* aA, float* bB,
                                          int* gidx, int GOFF) {
  constexpr int PR = (D + H) / 2;
#pragma unroll
  for (int j = 0; j < R; ++j)
    load_one<D, H>(64 * j + lane, Wih, Whh, bi, bh, w + j * PR, bias[j], sA[j], aA[j],
                   bB[j], gidx[j], GOFF);
}

// d3 split: wave owns ALL 4 gates of units UOFF..UOFF+31 (2 rows/lane):
// g = 2*j + (lane>>5), u = UOFF + (lane&31)  -> gate gather stays intra-wave.
template <int D, int H, int UOFF>
__device__ __forceinline__ void load_rows2(int lane, const float* Wih, const float* Whh,
                                           const float* bi, const float* bh, h2* w,
                                           float* bias, float* sA, float* aA, float* bB,
                                           int* gidx, int GOFF) {
  constexpr int PR = (D + H) / 2;
#pragma unroll
  for (int j = 0; j < 2; ++j) {
    const int g = 2 * j + (lane >> 5);
    const int u = UOFF + (lane & 31);
    load_one<D, H>(g * H + u, Wih, Whh, bi, bh, w + j * PR, bias[j], sA[j], aA[j], bB[j],
                   gidx[j], GOFF);
  }
}

template <int NQ>
__device__ __forceinline__ void fetch_q(const half_t* hb, uint4* q) {
  const uint4* p = (const uint4*)hb;
#pragma unroll
  for (int i = 0; i < NQ; ++i) q[i] = p[i];
}

template <int NQ>
__device__ __forceinline__ void dot_q(const h2* w, const uint4* q, float* a4) {
#pragma unroll
  for (int i = 0; i < NQ; ++i) {
    a4[0] = fdot2f(w[4 * i + 0], u2h(q[i].x), a4[0]);
    a4[1] = fdot2f(w[4 * i + 1], u2h(q[i].y), a4[1]);
    a4[2] = fdot2f(w[4 * i + 2], u2h(q[i].z), a4[2]);
    a4[3] = fdot2f(w[4 * i + 3], u2h(q[i].w), a4[3]);
  }
}

__device__ __forceinline__ float act_ev(float pre, float s, float a, float b) {
  float e = exp2f(s * pre);
  return fmaf(a, __builtin_amdgcn_rcpf(1.f + e), b);
}

// Gate gather (i,f,g,o at gsc[u*4..]) -> c,h update.
__device__ __forceinline__ float combine(const float* gu, float& c) {
  float4 g4 = *(const float4*)gu;
  c = fmaf(g4.y, c, g4.x * g4.z);
  float e2 = exp2f(-2.88539008f * c);
  return g4.w * fmaf(2.f, __builtin_amdgcn_rcpf(1.f + e2), -1.f);
}

// ===================== x -> f16 conversion =====================
__global__ __launch_bounds__(256) void cvt16(const float4* __restrict__ in,
                                             uint2* __restrict__ out, int n4) {
  int i = blockIdx.x * 256 + threadIdx.x;
  const int stride = gridDim.x * 256;
  union U { h2 h; uint32_t u; };
  for (; i < n4; i += stride) {
    float4 v = in[i];
    U a, b;
    a.h = pk2(v.x, v.y);
    b.h = pk2(v.z, v.w);
    out[i] = make_uint2(a.u, b.u);
  }
}

// ===================== Encoder: e1(64->48) e2(48->32) e3(32->16) =====================
// 512 blocks x 192 threads. wave0=e1 (skew 0), wave1=e2 (skew 1), wave2=e3 (skew 2).
template <int E1X>  // 0: x from f16 ws buffer (SMEM prefetch), 1: f32 direct
__global__ __launch_bounds__(192, 2) void enc_ker(
    const float* __restrict__ W0, const float* __restrict__ U0, const float* __restrict__ b0i, const float* __restrict__ b0h,
    const float* __restrict__ W1, const float* __restrict__ U1, const float* __restrict__ b1i, const float* __restrict__ b1h,
    const float* __restrict__ W2, const float* __restrict__ U2, const float* __restrict__ b2i, const float* __restrict__ b2h,
    const float* __restrict__ x32, const uint4* __restrict__ x16, float* __restrict__ lat,
    int T) {
  __shared__ __align__(16) half_t hb1[2][48];
  __shared__ __align__(16) half_t hb2[2][32];
  __shared__ __align__(16) half_t hb3[2][16];
  __shared__ __align__(16) float gsc[384];  // e1@0(192) e2@192(128) e3@320(64)

  const int tid = threadIdx.x, wv = tid >> 6, l = tid & 63, b = blockIdx.x;

  if (tid < 48) { hb1[0][tid] = (half_t)0.f; hb1[1][tid] = (half_t)0.f; }
  if (tid < 32) { hb2[0][tid] = (half_t)0.f; hb2[1][tid] = (half_t)0.f; }
  if (tid < 16) { hb3[0][tid] = (half_t)0.f; hb3[1][tid] = (half_t)0.f; }

  h2 w[168];
  float bias[3], sA[3], aA[3], bB[3];
  int gidx[3];
  float c = 0.f;

  if (wv == 0) load_rows<64, 48, 3>(l, W0, U0, b0i, b0h, w, bias, sA, aA, bB, gidx, 0);
  if (wv == 1) load_rows<48, 32, 2>(l, W1, U1, b1i, b1h, w, bias, sA, aA, bB, gidx, 192);
  if (wv == 2) load_rows<32, 16, 1>(l, W2, U2, b2i, b2h, w, bias, sA, aA, bB, gidx, 320);
  __syncthreads();

  uint4 xq[8];  // e1 x_t (64 f16), SMEM-prefetched one step ahead
  if (wv == 0) {
    if constexpr (E1X == 0) {
      const uint4* xr = x16 + (size_t)b * T * 8;
#pragma unroll
      for (int i = 0; i < 8; ++i) xq[i] = xr[i];
    }
  }

  for (int s = 0; s < T + 2; ++s) {
    const int par = s & 1;
    if (wv == 0) {
      const int t = s;
      if (t < T) {
        if constexpr (E1X == 1) {
          const float* xr = x32 + ((size_t)b * T + t) * 64;
          union U { h2 h; uint32_t u; };
#pragma unroll
          for (int i = 0; i < 8; ++i) {
            float4 a = ((const float4*)xr)[2 * i], q = ((const float4*)xr)[2 * i + 1];
            U w0, w1, w2, w3;
            w0.h = pk2(a.x, a.y); w1.h = pk2(a.z, a.w);
            w2.h = pk2(q.x, q.y); w3.h = pk2(q.z, q.w);
            xq[i] = make_uint4(w0.u, w1.u, w2.u, w3.u);
          }
        }
        uint4 hq[6];
        fetch_q<6>(hb1[par ^ 1], hq);
        float gv[3];
#pragma unroll
        for (int j = 0; j < 3; ++j) {
          float a4[4] = {bias[j], 0.f, 0.f, 0.f};
          dot_q<8>(w + j * 56, xq, a4);
          dot_q<6>(w + j * 56 + 32, hq, a4);
          gv[j] = act_ev((a4[0] + a4[1]) + (a4[2] + a4[3]), sA[j], aA[j], bB[j]);
        }
        if constexpr (E1X == 0) {  // prefetch x(t+1) while gates settle
          if (t + 1 < T) {
            const uint4* xr = x16 + ((size_t)b * T + t + 1) * 8;
#pragma unroll
            for (int i = 0; i < 8; ++i) xq[i] = xr[i];
          }
        }
#pragma unroll
        for (int j = 0; j < 3; ++j) gsc[gidx[j]] = gv[j];
        WAVE_SYNC();
        if (l < 48) hb1[par][l] = (half_t)combine(&gsc[l * 4], c);
      }
    } else if (wv == 1) {
      const int t = s - 1;
      if (t >= 0 && t < T) {
        uint4 xv[6], hq[4];
        fetch_q<6>(hb1[par ^ 1], xv);
        fetch_q<4>(hb2[par ^ 1], hq);
        float gv[2];
#pragma unroll
        for (int j = 0; j < 2; ++j) {
          float a4[4] = {bias[j], 0.f, 0.f, 0.f};
          dot_q<6>(w + j * 40, xv, a4);
          dot_q<4>(w + j * 40 + 24, hq, a4);
          gv[j] = act_ev((a4[0] + a4[1]) + (a4[2] + a4[3]), sA[j], aA[j], bB[j]);
        }
#pragma unroll
        for (int j = 0; j < 2; ++j) gsc[gidx[j]] = gv[j];
        WAVE_SYNC();
        if (l < 32) hb2[par][l] = (half_t)combine(&gsc[192 + l * 4], c);
      }
    } else {
      const int t = s - 2;
      if (t >= 0 && t < T) {
        uint4 xv[4], hq[2];
        fetch_q<4>(hb2[par ^ 1], xv);
        fetch_q<2>(hb3[par ^ 1], hq);
        float a4[4] = {bias[0], 0.f, 0.f, 0.f};
        dot_q<4>(w, xv, a4);
        dot_q<2>(w + 16, hq, a4);
        float gv = act_ev((a4[0] + a4[1]) + (a4[2] + a4[3]), sA[0], aA[0], bB[0]);
        gsc[gidx[0]] = gv;
        WAVE_SYNC();
        if (l < 16) {
          float h = combine(&gsc[320 + l * 4], c);
          hb3[par][l] = (half_t)h;
          if (t == T - 1) lat[(size_t)b * 16 + l] = h;
        }
      }
    }
    __syncthreads();
  }
}

// ===================== Decoder: d1(16->32,folded) d2(32->48) d3(48->64) =====================
// 512 blocks x 256 threads. wave0=d1(skew0) wave1=d2(skew1) wave2,3=d3(skew2, unit halves).
__global__ __launch_bounds__(256, 2) void dec_ker(
    const float* __restrict__ W3, const float* __restrict__ U3, const float* __restrict__ b3i, const float* __restrict__ b3h,
    const float* __restrict__ W4, const float* __restrict__ U4, const float* __restrict__ b4i, const float* __restrict__ b4h,
    const float* __restrict__ W5, const float* __restrict__ U5, const float* __restrict__ b5i, const float* __restrict__ b5h,
    const float* __restrict__ lat, float* __restrict__ out, int T) {
  __shared__ __align__(16) half_t hb1[2][32];
  __shared__ __align__(16) half_t hb2[2][48];
  __shared__ __align__(16) half_t hb3[2][64];
  __shared__ __align__(16) float gsc[576];  // d1@0(128) d2@128(192) d3@320(256)

  const int tid = threadIdx.x, wv = tid >> 6, l = tid & 63, b = blockIdx.x;

  if (tid < 32) { hb1[0][tid] = (half_t)0.f; hb1[1][tid] = (half_t)0.f; }
  if (tid < 48) { hb2[0][tid] = (half_t)0.f; hb2[1][tid] = (half_t)0.f; }
  if (tid < 64) { hb3[0][tid] = (half_t)0.f; hb3[1][tid] = (half_t)0.f; }

  h2 w[120];
  float bias[3], sA[3], aA[3], bB[3];
  int gidx[3];
  float c = 0.f;

  if (wv == 0) {
    load_rows<0, 32, 2>(l, W3, U3, b3i, b3h, w, bias, sA, aA, bB, gidx, 0);
    // fold Wih_d1 @ latent into the bias (latent constant over time)
#pragma unroll
    for (int j = 0; j < 2; ++j) {
      const int r = 64 * j + l;
      const float* wr = W3 + (size_t)r * 16;
      const float* lt = lat + (size_t)b * 16;
      float s0 = 0.f;
#pragma unroll
      for (int d = 0; d < 16; ++d) s0 = fmaf(wr[d], lt[d], s0);
      bias[j] += s0;
    }
  }
  if (wv == 1) load_rows<32, 48, 3>(l, W4, U4, b4i, b4h, w, bias, sA, aA, bB, gidx, 128);
  if (wv == 2) load_rows2<48, 64, 0>(l, W5, U5, b5i, b5h, w, bias, sA, aA, bB, gidx, 320);
  if (wv == 3) load_rows2<48, 64, 32>(l, W5, U5, b5i, b5h, w, bias, sA, aA, bB, gidx, 320);
  __syncthreads();

  for (int s = 0; s < T + 2; ++s) {
    const int par = s & 1;
    if (wv == 0) {
      const int t = s;
      if (t < T) {
        uint4 hq[4];
        fetch_q<4>(hb1[par ^ 1], hq);
        float gv[2];
#pragma unroll
        for (int j = 0; j < 2; ++j) {
          float a4[4] = {bias[j], 0.f, 0.f, 0.f};
          dot_q<4>(w + j * 16, hq, a4);
          gv[j] = act_ev((a4[0] + a4[1]) + (a4[2] + a4[3]), sA[j], aA[j], bB[j]);
        }
#pragma unroll
        for (int j = 0; j < 2; ++j) gsc[gidx[j]] = gv[j];
        WAVE_SYNC();
        if (l < 32) hb1[par][l] = (half_t)combine(&gsc[l * 4], c);
      }
    } else if (wv == 1) {
      const int t = s - 1;
      if (t >= 0 && t < T) {
        uint4 xv[4], hq[6];
        fetch_q<4>(hb1[par ^ 1], xv);
        fetch_q<6>(hb2[par ^ 1], hq);
        float gv[3];
#pragma unroll
        for (int j = 0; j < 3; ++j) {
          float a4[4] = {bias[j], 0.f, 0.f, 0.f};
          dot_q<4>(w + j * 40, xv, a4);
          dot_q<6>(w + j * 40 + 16, hq, a4);
          gv[j] = act_ev((a4[0] + a4[1]) + (a4[2] + a4[3]), sA[j], aA[j], bB[j]);
        }
#pragma unroll
        for (int j = 0; j < 3; ++j) gsc[gidx[j]] = gv[j];
        WAVE_SYNC();
        if (l < 48) hb2[par][l] = (half_t)combine(&gsc[128 + l * 4], c);
      }
    } else {
      const int t = s - 2;
      if (t >= 0 && t < T) {
        uint4 xv[6], hq[8];
        fetch_q<6>(hb2[par ^ 1], xv);
        fetch_q<8>(hb3[par ^ 1], hq);
        float gv[2];
#pragma unroll
        for (int j = 0; j < 2; ++j) {
          float a4[4] = {bias[j], 0.f, 0.f, 0.f};
          dot_q<6>(w + j * 56, xv, a4);
          dot_q<8>(w + j * 56 + 24, hq, a4);
          gv[j] = act_ev((a4[0] + a4[1]) + (a4[2] + a4[3]), sA[j], aA[j], bB[j]);
        }
#pragma unroll
        for (int j = 0; j < 2; ++j) gsc[gidx[j]] = gv[j];
        WAVE_SYNC();
        if (l < 32) {
          const int u = (wv == 2 ? 0 : 32) + l;
          float h = combine(&gsc[320 + u * 4], c);
          hb3[par][u] = (half_t)h;
          out[((size_t)b * T + t) * 64 + u] = h;
        }
      }
    }
    __syncthreads();
  }
}

extern "C" void kernel_launch(void* const* d_in, const int* in_sizes, int n_in,
                              void* d_out, int out_size, void* d_ws, size_t ws_size,
                              hipStream_t stream) {
  (void)in_sizes; (void)n_in; (void)out_size;
  const float* x = (const float*)d_in[0];
  const float *W[6], *U[6], *Bi[6], *Bh[6];
  for (int lyr = 0; lyr < 6; ++lyr) {
    W[lyr]  = (const float*)d_in[1 + 4 * lyr + 0];
    U[lyr]  = (const float*)d_in[1 + 4 * lyr + 1];
    Bi[lyr] = (const float*)d_in[1 + 4 * lyr + 2];
    Bh[lyr] = (const float*)d_in[1 + 4 * lyr + 3];
  }
  float* out = (float*)d_out;
  const int T = 512;
  const size_t n_x = (size_t)512 * 512 * 64;          // 16.8M elems
  const size_t szX16 = n_x * 2;                       // 33.6 MB
  const size_t szLat = (size_t)512 * 16 * 4;          // 32 KB
  char* ws = (char*)d_ws;

  if (ws_size >= szX16 + szLat) {
    uint2* x16 = (uint2*)ws;
    float* lat = (float*)(ws + szX16);
    cvt16<<<dim3(2048), dim3(256), 0, stream>>>((const float4*)x, x16, (int)(n_x / 4));
    enc_ker<0><<<dim3(512), dim3(192), 0, stream>>>(
        W[0], U[0], Bi[0], Bh[0], W[1], U[1], Bi[1], Bh[1], W[2], U[2], Bi[2], Bh[2],
        x, (const uint4*)x16, lat, T);
    dec_ker<<<dim3(512), dim3(256), 0, stream>>>(
        W[3], U[3], Bi[3], Bh[3], W[4], U[4], Bi[4], Bh[4], W[5], U[5], Bi[5], Bh[5],
        lat, out, T);
  } else {
    float* lat = (float*)ws;  // fallback: only 32KB of ws needed
    enc_ker<1><<<dim3(512), dim3(192), 0, stream>>>(
        W[0], U[0], Bi[0], Bh[0], W[1], U[1], Bi[1], Bh[1], W[2], U[2], Bi[2], Bh[2],
        x, nullptr, lat, T);
    dec_ker<<<dim3(512), dim3(256), 0, stream>>>(
        W[3], U[3], Bi[3], Bh[3], W[4], U[4], Bi[4], Bh[4], W[5], U[5], Bi[5], Bh[5],
        lat, out, T);
  }
}

// Round 6
// 930.179 us; speedup vs baseline: 2.8059x; 1.8997x over previous
//
#include <hip/hip_runtime.h>
#include <hip/hip_bf16.h>
#include <cstdint>
#include <cstddef>

typedef _Float16 half_t;
typedef decltype(__builtin_amdgcn_cvt_pkrtz(0.f, 0.f)) h2;  // v2f16

__device__ __forceinline__ h2 pk2(float a, float b) { return __builtin_amdgcn_cvt_pkrtz(a, b); }
__device__ __forceinline__ float fdot2f(h2 a, h2 b, float c) { return __builtin_amdgcn_fdot2(a, b, c, false); }
__device__ __forceinline__ h2 u2h(uint32_t u) { union { uint32_t u; h2 h; } v; v.u = u; return v.h; }

// Intra-wave LDS drain (ds ops of THIS wave).
#define WAVE_SYNC() asm volatile("s_waitcnt lgkmcnt(0)" ::: "memory")
// Block barrier WITHOUT vmcnt drain: producer global loads stay in flight.
#define BLOCK_SYNC()                                   \
  do {                                                 \
    asm volatile("s_waitcnt lgkmcnt(0)" ::: "memory"); \
    __builtin_amdgcn_s_barrier();                      \
    asm volatile("" ::: "memory");                     \
  } while (0)

template <int NQ>
__device__ __forceinline__ void fetch_q(const half_t* hb, uint4* q) {
  const uint4* p = (const uint4*)hb;
#pragma unroll
  for (int i = 0; i < NQ; ++i) q[i] = p[i];
}

template <int NQ>
__device__ __forceinline__ void dot_q(const h2* w, const uint4* q, float* a4) {
#pragma unroll
  for (int i = 0; i < NQ; ++i) {
    a4[0] = fdot2f(w[4 * i + 0], u2h(q[i].x), a4[0]);
    a4[1] = fdot2f(w[4 * i + 1], u2h(q[i].y), a4[1]);
    a4[2] = fdot2f(w[4 * i + 2], u2h(q[i].z), a4[2]);
    a4[3] = fdot2f(w[4 * i + 3], u2h(q[i].w), a4[3]);
  }
}

__device__ __forceinline__ void load_row_h2(const float* src, int nf, h2* dst) {
  const float2* s2 = (const float2*)src;
  for (int p = 0; p < nf / 2; ++p) { float2 v = s2[p]; dst[p] = pk2(v.x, v.y); }
}

__device__ __forceinline__ void gconst(int gt, float& s, float& a, float& b) {
  const bool isT = (gt == 2);
  s = isT ? -2.88539008f : -1.44269504f;
  a = isT ? 2.f : 1.f;
  b = isT ? -1.f : 0.f;
}

__device__ __forceinline__ float act_ev(float pre, float s, float a, float b) {
  float e = exp2f(s * pre);
  return fmaf(a, __builtin_amdgcn_rcpf(1.f + e), b);
}

__device__ __forceinline__ float comb4(float gi, float gf, float gg, float go, float& c) {
  c = fmaf(gf, c, gi * gg);
  float e2 = exp2f(-2.88539008f * c);
  return go * fmaf(2.f, __builtin_amdgcn_rcpf(1.f + e2), -1.f);
}

// Pair layers (pow2 H): lane l<32 computed gates (i,f) of unit u, lane l+32
// computed (g,o) of the same unit. One shfl_xor(32) pair completes the set.
__device__ __forceinline__ float pair_combine(float gv0, float gv1, int l, float& c) {
  float sw0 = __shfl_xor(gv0, 32, 64);
  float sw1 = __shfl_xor(gv1, 32, 64);
  const bool lo = (l < 32);
  float gi = lo ? gv0 : sw0, gf = lo ? gv1 : sw1;
  float gg = lo ? sw0 : gv0, go = lo ? sw1 : gv1;
  return comb4(gi, gf, gg, go, c);
}

// ===================== Encoder =====================
// 512 blocks x 256 threads. wv0=e1-rec(skew0) wv1=e2(skew1) wv2=e3(skew2)
// wv3=producer (x load + e1 x-GEMM, 1-2 steps ahead).
__global__ __launch_bounds__(256, 2) void enc_ker(
    const float* __restrict__ W0, const float* __restrict__ U0, const float* __restrict__ b0i, const float* __restrict__ b0h,
    const float* __restrict__ W1, const float* __restrict__ U1, const float* __restrict__ b1i, const float* __restrict__ b1h,
    const float* __restrict__ W2, const float* __restrict__ U2, const float* __restrict__ b2i, const float* __restrict__ b2h,
    const float* __restrict__ x, float* __restrict__ lat, int T) {
  __shared__ __align__(16) half_t hb1[2][48];
  __shared__ __align__(16) half_t hb2[2][32];
  __shared__ __align__(16) half_t hb3[2][16];
  __shared__ __align__(16) float gsc[192];     // e1 gate exchange, word r
  __shared__ __align__(16) float xrow[2][64];  // producer x staging
  __shared__ __align__(16) float xg[2][192];   // producer -> e1 (bias included)

  const int tid = threadIdx.x, wv = tid >> 6, l = tid & 63, b = blockIdx.x;

  if (tid < 48) { hb1[0][tid] = (half_t)0.f; hb1[1][tid] = (half_t)0.f; }
  if (tid < 32) { hb2[0][tid] = (half_t)0.f; hb2[1][tid] = (half_t)0.f; }
  if (tid < 16) { hb3[0][tid] = (half_t)0.f; hb3[1][tid] = (half_t)0.f; }

  h2 w[96];
  float bias[3], sA[3], aA[3], bB[3];
  float c = 0.f;
  float va = 0.f, vb = 0.f;  // producer prefetch regs

  if (wv == 0) {  // e1 recurrent: rows 64j+l, Whh only (x-part via producer)
#pragma unroll
    for (int j = 0; j < 3; ++j) {
      const int r = 64 * j + l;
      load_row_h2(U0 + (size_t)r * 48, 48, w + j * 24);
      gconst(r / 48, sA[j], aA[j], bB[j]);
    }
  } else if (wv == 1) {  // e2: H=32 pair layer, rows (g0+j)*32+u
    const int u = l & 31, g0 = (l < 32) ? 0 : 2;
#pragma unroll
    for (int j = 0; j < 2; ++j) {
      const int r = (g0 + j) * 32 + u;
      load_row_h2(W1 + (size_t)r * 48, 48, w + j * 40);
      load_row_h2(U1 + (size_t)r * 32, 32, w + j * 40 + 24);
      bias[j] = b1i[r] + b1h[r];
      gconst(g0 + j, sA[j], aA[j], bB[j]);
    }
  } else if (wv == 2) {  // e3: H=16, 1 row/lane, r = l
    load_row_h2(W2 + (size_t)l * 32, 32, w);
    load_row_h2(U2 + (size_t)l * 16, 16, w + 16);
    bias[0] = b2i[l] + b2h[l];
    gconst(l >> 4, sA[0], aA[0], bB[0]);
  } else {  // producer: Wih_e1 rows 64j+l (bias folded into xg)
#pragma unroll
    for (int j = 0; j < 3; ++j) {
      const int r = 64 * j + l;
      load_row_h2(W0 + (size_t)r * 64, 64, w + j * 32);
      bias[j] = b0i[r] + b0h[r];
    }
    // prologue: xrow[0]=x0, xrow[1]=x1; va=x2, vb=x3; xg[0] for t=0
    const float* xb = x + (size_t)b * T * 64 + l;
    float v0 = xb[0], v1 = xb[64];
    xrow[0][l] = v0;
    xrow[1][l] = v1;
    va = xb[2 * 64];
    vb = xb[3 * 64];
    WAVE_SYNC();
    {
      const float4* xr4 = (const float4*)&xrow[0][0];
      float a0 = bias[0], a1 = bias[1], a2 = bias[2];
#pragma unroll
      for (int i = 0; i < 16; ++i) {
        float4 v = xr4[i];
        h2 x0 = pk2(v.x, v.y), x1 = pk2(v.z, v.w);
        a0 = fdot2f(w[2 * i], x0, a0);      a0 = fdot2f(w[2 * i + 1], x1, a0);
        a1 = fdot2f(w[32 + 2 * i], x0, a1); a1 = fdot2f(w[33 + 2 * i], x1, a1);
        a2 = fdot2f(w[64 + 2 * i], x0, a2); a2 = fdot2f(w[65 + 2 * i], x1, a2);
      }
      xg[0][l] = a0; xg[0][64 + l] = a1; xg[0][128 + l] = a2;
    }
  }
  BLOCK_SYNC();

  for (int s = 0; s < T + 2; ++s) {
    const int p = s & 1, q = p ^ 1;
    if (wv == 0) {
      const int t = s;
      if (t < T) {
        float xgv[3];
#pragma unroll
        for (int j = 0; j < 3; ++j) xgv[j] = xg[p][64 * j + l];
        uint4 hq[6];
        fetch_q<6>(&hb1[q][0], hq);
        float gv[3];
#pragma unroll
        for (int j = 0; j < 3; ++j) {
          float a4[4] = {xgv[j], 0.f, 0.f, 0.f};
          dot_q<6>(w + j * 24, hq, a4);
          gv[j] = act_ev((a4[0] + a4[1]) + (a4[2] + a4[3]), sA[j], aA[j], bB[j]);
        }
#pragma unroll
        for (int j = 0; j < 3; ++j) gsc[64 * j + l] = gv[j];
        WAVE_SYNC();
        if (l < 48) {
          float h = comb4(gsc[l], gsc[48 + l], gsc[96 + l], gsc[144 + l], c);
          hb1[p][l] = (half_t)h;
        }
      }
    } else if (wv == 1) {
      const int t = s - 1;
      if (t >= 0 && t < T) {
        uint4 xv[6], hq[4];
        fetch_q<6>(&hb1[q][0], xv);
        fetch_q<4>(&hb2[q][0], hq);
        float gv[2];
#pragma unroll
        for (int j = 0; j < 2; ++j) {
          float a4[4] = {bias[j], 0.f, 0.f, 0.f};
          dot_q<6>(w + j * 40, xv, a4);
          dot_q<4>(w + j * 40 + 24, hq, a4);
          gv[j] = act_ev((a4[0] + a4[1]) + (a4[2] + a4[3]), sA[j], aA[j], bB[j]);
        }
        float h = pair_combine(gv[0], gv[1], l, c);
        if (l < 32) hb2[p][l] = (half_t)h;
      }
    } else if (wv == 2) {
      const int t = s - 2;
      if (t >= 0 && t < T) {
        uint4 xv[4], hq[2];
        fetch_q<4>(&hb2[q][0], xv);
        fetch_q<2>(&hb3[q][0], hq);
        float a4[4] = {bias[0], 0.f, 0.f, 0.f};
        dot_q<4>(w, xv, a4);
        dot_q<2>(w + 16, hq, a4);
        float gv = act_ev((a4[0] + a4[1]) + (a4[2] + a4[3]), sA[0], aA[0], bB[0]);
        float s1 = __shfl_xor(gv, 16, 64);
        float r0 = __shfl_xor(gv, 32, 64);
        float r1 = __shfl_xor(s1, 32, 64);
        // canonical for lanes<16: (i,f,g,o) = (gv,s1,r0,r1); others harmless
        float h = comb4(gv, s1, r0, r1, c);
        if (l < 16) {
          hb3[p][l] = (half_t)h;
          if (t == T - 1) lat[(size_t)b * 16 + l] = h;
        }
      }
    } else {
      // producer: stage x[s+2] into xrow[p]; compute xg for t=s+1 from xrow[q]
      if (s + 2 < T) {
        float vw = (s & 1) ? vb : va;
        xrow[p][l] = vw;
        if (s + 4 < T) {
          float nv = x[((size_t)b * T + s + 4) * 64 + l];
          if (s & 1) vb = nv; else va = nv;
        }
      }
      if (s + 1 < T) {
        WAVE_SYNC();  // (xrow[q] written last step by self; xg write ordering)
        const float4* xr4 = (const float4*)&xrow[q][0];
        float a0 = bias[0], a1 = bias[1], a2 = bias[2];
#pragma unroll
        for (int i = 0; i < 16; ++i) {
          float4 v = xr4[i];
          h2 x0 = pk2(v.x, v.y), x1 = pk2(v.z, v.w);
          a0 = fdot2f(w[2 * i], x0, a0);      a0 = fdot2f(w[2 * i + 1], x1, a0);
          a1 = fdot2f(w[32 + 2 * i], x0, a1); a1 = fdot2f(w[33 + 2 * i], x1, a1);
          a2 = fdot2f(w[64 + 2 * i], x0, a2); a2 = fdot2f(w[65 + 2 * i], x1, a2);
        }
        xg[q][l] = a0; xg[q][64 + l] = a1; xg[q][128 + l] = a2;
      }
    }
    BLOCK_SYNC();
  }
}

// ===================== Decoder =====================
// 512 blocks x 256 threads. wv0=d1(skew0,folded latent) wv1=d2(skew1)
// wv2=d3 units 0-31 (skew2) wv3=d3 units 32-63 (skew2).
__global__ __launch_bounds__(256, 2) void dec_ker(
    const float* __restrict__ W3, const float* __restrict__ U3, const float* __restrict__ b3i, const float* __restrict__ b3h,
    const float* __restrict__ W4, const float* __restrict__ U4, const float* __restrict__ b4i, const float* __restrict__ b4h,
    const float* __restrict__ W5, const float* __restrict__ U5, const float* __restrict__ b5i, const float* __restrict__ b5h,
    const float* __restrict__ lat, float* __restrict__ out, int T) {
  __shared__ __align__(16) half_t hb1[2][32];
  __shared__ __align__(16) half_t hb2[2][48];
  __shared__ __align__(16) half_t hb3[2][64];
  __shared__ __align__(16) float gsc[192];  // d2 gate exchange

  const int tid = threadIdx.x, wv = tid >> 6, l = tid & 63, b = blockIdx.x;

  if (tid < 32) { hb1[0][tid] = (half_t)0.f; hb1[1][tid] = (half_t)0.f; }
  if (tid < 48) { hb2[0][tid] = (half_t)0.f; hb2[1][tid] = (half_t)0.f; }
  if (tid < 64) { hb3[0][tid] = (half_t)0.f; hb3[1][tid] = (half_t)0.f; }

  h2 w[120];
  float bias[3], sA[3], aA[3], bB[3];
  float c = 0.f;

  if (wv == 0) {  // d1: H=32 pair layer, Whh only; latent folded into bias
    const int u = l & 31, g0 = (l < 32) ? 0 : 2;
    const float* lt = lat + (size_t)b * 16;
#pragma unroll
    for (int j = 0; j < 2; ++j) {
      const int r = (g0 + j) * 32 + u;
      load_row_h2(U3 + (size_t)r * 32, 32, w + j * 16);
      float s0 = b3i[r] + b3h[r];
      const float* wr = W3 + (size_t)r * 16;
#pragma unroll
      for (int d = 0; d < 16; ++d) s0 = fmaf(wr[d], lt[d], s0);
      bias[j] = s0;
      gconst(g0 + j, sA[j], aA[j], bB[j]);
    }
  } else if (wv == 1) {  // d2: H=48, rows 64j+l, LDS exchange
#pragma unroll
    for (int j = 0; j < 3; ++j) {
      const int r = 64 * j + l;
      load_row_h2(W4 + (size_t)r * 32, 32, w + j * 40);
      load_row_h2(U4 + (size_t)r * 48, 48, w + j * 40 + 16);
      bias[j] = b4i[r] + b4h[r];
      gconst(r / 48, sA[j], aA[j], bB[j]);
    }
  } else {  // d3: H=64 pair layer, two waves by unit half
    const int u = (l & 31) + ((wv == 3) ? 32 : 0);
    const int g0 = (l < 32) ? 0 : 2;
#pragma unroll
    for (int j = 0; j < 2; ++j) {
      const int r = (g0 + j) * 64 + u;
      load_row_h2(W5 + (size_t)r * 48, 48, w + j * 56);
      load_row_h2(U5 + (size_t)r * 64, 64, w + j * 56 + 24);
      bias[j] = b5i[r] + b5h[r];
      gconst(g0 + j, sA[j], aA[j], bB[j]);
    }
  }
  BLOCK_SYNC();

  for (int s = 0; s < T + 2; ++s) {
    const int p = s & 1, q = p ^ 1;
    if (wv == 0) {
      const int t = s;
      if (t < T) {
        uint4 hq[4];
        fetch_q<4>(&hb1[q][0], hq);
        float gv[2];
#pragma unroll
        for (int j = 0; j < 2; ++j) {
          float a4[4] = {bias[j], 0.f, 0.f, 0.f};
          dot_q<4>(w + j * 16, hq, a4);
          gv[j] = act_ev((a4[0] + a4[1]) + (a4[2] + a4[3]), sA[j], aA[j], bB[j]);
        }
        float h = pair_combine(gv[0], gv[1], l, c);
        if (l < 32) hb1[p][l] = (half_t)h;
      }
    } else if (wv == 1) {
      const int t = s - 1;
      if (t >= 0 && t < T) {
        uint4 xv[4], hq[6];
        fetch_q<4>(&hb1[q][0], xv);
        fetch_q<6>(&hb2[q][0], hq);
        float gv[3];
#pragma unroll
        for (int j = 0; j < 3; ++j) {
          float a4[4] = {bias[j], 0.f, 0.f, 0.f};
          dot_q<4>(w + j * 40, xv, a4);
          dot_q<6>(w + j * 40 + 16, hq, a4);
          gv[j] = act_ev((a4[0] + a4[1]) + (a4[2] + a4[3]), sA[j], aA[j], bB[j]);
        }
#pragma unroll
        for (int j = 0; j < 3; ++j) gsc[64 * j + l] = gv[j];
        WAVE_SYNC();
        if (l < 48) {
          float h = comb4(gsc[l], gsc[48 + l], gsc[96 + l], gsc[144 + l], c);
          hb2[p][l] = (half_t)h;
        }
      }
    } else {
      const int t = s - 2;
      if (t >= 0 && t < T) {
        uint4 xv[6], hq[8];
        fetch_q<6>(&hb2[q][0], xv);
        fetch_q<8>(&hb3[q][0], hq);
        float gv[2];
#pragma unroll
        for (int j = 0; j < 2; ++j) {
          float a4[4] = {bias[j], 0.f, 0.f, 0.f};
          dot_q<6>(w + j * 56, xv, a4);
          dot_q<8>(w + j * 56 + 24, hq, a4);
          gv[j] = act_ev((a4[0] + a4[1]) + (a4[2] + a4[3]), sA[j], aA[j], bB[j]);
        }
        float h = pair_combine(gv[0], gv[1], l, c);
        if (l < 32) {
          const int u = (l & 31) + ((wv == 3) ? 32 : 0);
          hb3[p][u] = (half_t)h;
          out[((size_t)b * T + t) * 64 + u] = h;
        }
      }
    }
    BLOCK_SYNC();
  }
}

extern "C" void kernel_launch(void* const* d_in, const int* in_sizes, int n_in,
                              void* d_out, int out_size, void* d_ws, size_t ws_size,
                              hipStream_t stream) {
  (void)in_sizes; (void)n_in; (void)out_size; (void)ws_size;
  const float* x = (const float*)d_in[0];
  const float *W[6], *U[6], *Bi[6], *Bh[6];
  for (int lyr = 0; lyr < 6; ++lyr) {
    W[lyr]  = (const float*)d_in[1 + 4 * lyr + 0];
    U[lyr]  = (const float*)d_in[1 + 4 * lyr + 1];
    Bi[lyr] = (const float*)d_in[1 + 4 * lyr + 2];
    Bh[lyr] = (const float*)d_in[1 + 4 * lyr + 3];
  }
  float* out = (float*)d_out;
  const int T = 512;
  float* lat = (float*)d_ws;  // 32 KB

  enc_ker<<<dim3(512), dim3(256), 0, stream>>>(
      W[0], U[0], Bi[0], Bh[0], W[1], U[1], Bi[1], Bh[1], W[2], U[2], Bi[2], Bh[2],
      x, lat, T);
  dec_ker<<<dim3(512), dim3(256), 0, stream>>>(
      W[3], U[3], Bi[3], Bh[3], W[4], U[4], Bi[4], Bh[4], W[5], U[5], Bi[5], Bh[5],
      lat, out, T);
}

// Round 7
// 791.912 us; speedup vs baseline: 3.2958x; 1.1746x over previous
//
#include <hip/hip_runtime.h>
#include <hip/hip_bf16.h>
#include <cstdint>
#include <cstddef>

typedef _Float16 half_t;
typedef decltype(__builtin_amdgcn_cvt_pkrtz(0.f, 0.f)) h2;  // v2f16

__device__ __forceinline__ h2 pk2(float a, float b) { return __builtin_amdgcn_cvt_pkrtz(a, b); }
__device__ __forceinline__ float fdot2f(h2 a, h2 b, float c) { return __builtin_amdgcn_fdot2(a, b, c, false); }
__device__ __forceinline__ h2 u2h(uint32_t u) { union { uint32_t u; h2 h; } v; v.u = u; return v.h; }

#define WAVE_SYNC() asm volatile("s_waitcnt lgkmcnt(0)" ::: "memory")
// Block barrier WITHOUT vmcnt drain: producer global loads stay in flight.
#define BLOCK_SYNC()                                   \
  do {                                                 \
    asm volatile("s_waitcnt lgkmcnt(0)" ::: "memory"); \
    __builtin_amdgcn_s_barrier();                      \
    asm volatile("" ::: "memory");                     \
  } while (0)

template <int NQ>
__device__ __forceinline__ void fetch_q(const half_t* hb, uint4* q) {
  const uint4* p = (const uint4*)hb;
#pragma unroll
  for (int i = 0; i < NQ; ++i) q[i] = p[i];
}

// 8 f16-MACs per uint4, two interleaved accumulators.
template <int NQ>
__device__ __forceinline__ void dot2acc(const h2* w, const uint4* q, float& a0, float& a1) {
#pragma unroll
  for (int i = 0; i < NQ; ++i) {
    a0 = fdot2f(w[4 * i + 0], u2h(q[i].x), a0);
    a1 = fdot2f(w[4 * i + 1], u2h(q[i].y), a1);
    a0 = fdot2f(w[4 * i + 2], u2h(q[i].z), a0);
    a1 = fdot2f(w[4 * i + 3], u2h(q[i].w), a1);
  }
}

__device__ __forceinline__ void load_row_h2(const float* src, int nf, h2* dst) {
  const float2* s2 = (const float2*)src;
  for (int p = 0; p < nf / 2; ++p) { float2 v = s2[p]; dst[p] = pk2(v.x, v.y); }
}

__device__ __forceinline__ void gconst(int gt, float& s, float& a, float& b) {
  const bool isT = (gt == 2);
  s = isT ? -2.88539008f : -1.44269504f;
  a = isT ? 2.f : 1.f;
  b = isT ? -1.f : 0.f;
}

__device__ __forceinline__ float act_sig(float x) {
  float e = exp2f(-1.44269504f * x);
  return __builtin_amdgcn_rcpf(1.f + e);
}
__device__ __forceinline__ float act_tanh(float x) {
  float e = exp2f(-2.88539008f * x);
  return fmaf(2.f, __builtin_amdgcn_rcpf(1.f + e), -1.f);
}
__device__ __forceinline__ float act_rt(float x, float s, float a, float b) {
  float e = exp2f(s * x);
  return fmaf(a, __builtin_amdgcn_rcpf(1.f + e), b);
}

__device__ __forceinline__ float comb4(float gi, float gf, float gg, float go, float& c) {
  c = fmaf(gf, c, gi * gg);
  float e2 = exp2f(-2.88539008f * c);
  return go * fmaf(2.f, __builtin_amdgcn_rcpf(1.f + e2), -1.f);
}

// Pair layers (pow2 H): lane l<32 computed gates (i,f) of unit u, lane l+32
// computed (g,o) of the same unit. One shfl_xor(32) pair completes the set.
__device__ __forceinline__ float pair_combine(float gv0, float gv1, int l, float& c) {
  float sw0 = __shfl_xor(gv0, 32, 64);
  float sw1 = __shfl_xor(gv1, 32, 64);
  const bool lo = (l < 32);
  float gi = lo ? gv0 : sw0, gf = lo ? gv1 : sw1;
  float gg = lo ? sw0 : gv0, go = lo ? sw1 : gv1;
  return comb4(gi, gf, gg, go, c);
}

// ===================== Encoder =====================
// 512 blocks x 256 threads.
// wv0 = e1-rec  (unit-per-lane, H=48: lane u<48 owns all 4 gates; 96 h-dots)
// wv1 = e2      (pair, 80 dots)   skew 1
// wv2 = e3      (24 dots + shfl)  skew 2
// wv3 = producer (x load f16-packed + e1 x-GEMM, 96 dots, 1 step ahead)
__global__ __launch_bounds__(256, 2) void enc_ker(
    const float* __restrict__ W0, const float* __restrict__ U0, const float* __restrict__ b0i, const float* __restrict__ b0h,
    const float* __restrict__ W1, const float* __restrict__ U1, const float* __restrict__ b1i, const float* __restrict__ b1h,
    const float* __restrict__ W2, const float* __restrict__ U2, const float* __restrict__ b2i, const float* __restrict__ b2h,
    const float* __restrict__ x, float* __restrict__ lat, int T) {
  __shared__ __align__(16) half_t hb1[2][48];
  __shared__ __align__(16) half_t hb2[2][32];
  __shared__ __align__(16) half_t hb3[2][16];
  __shared__ __align__(16) uint32_t xrow16[2][32];  // x_t as packed f16 pairs
  __shared__ __align__(16) float xg1[2][192];       // producer -> e1 (bias folded)

  const int tid = threadIdx.x, wv = tid >> 6, l = tid & 63, b = blockIdx.x;
  const int uu = (l < 48) ? l : 47;  // e1 unit (clamped for idle lanes)

  if (tid < 48) { hb1[0][tid] = (half_t)0.f; hb1[1][tid] = (half_t)0.f; }
  if (tid < 32) { hb2[0][tid] = (half_t)0.f; hb2[1][tid] = (half_t)0.f; }
  if (tid < 16) { hb3[0][tid] = (half_t)0.f; hb3[1][tid] = (half_t)0.f; }

  h2 w[96];
  float bias[3] = {0.f, 0.f, 0.f};
  float sA[2], aA[2], bB[2];
  float c = 0.f;
  float2 va = {0.f, 0.f}, vb = {0.f, 0.f};
  const float2* xp = nullptr;

  if (wv == 0) {  // e1-rec: rows j*48+uu of Whh only
#pragma unroll
    for (int j = 0; j < 4; ++j)
      load_row_h2(U0 + (size_t)(j * 48 + uu) * 48, 48, w + j * 24);
  } else if (wv == 1) {  // e2 pair
    const int u = l & 31, g0 = (l < 32) ? 0 : 2;
#pragma unroll
    for (int j = 0; j < 2; ++j) {
      const int r = (g0 + j) * 32 + u;
      load_row_h2(W1 + (size_t)r * 48, 48, w + j * 40);
      load_row_h2(U1 + (size_t)r * 32, 32, w + j * 40 + 24);
      bias[j] = b1i[r] + b1h[r];
      gconst(g0 + j, sA[j], aA[j], bB[j]);
    }
  } else if (wv == 2) {  // e3: row r=l
    load_row_h2(W2 + (size_t)l * 32, 32, w);
    load_row_h2(U2 + (size_t)l * 16, 16, w + 16);
    bias[0] = b2i[l] + b2h[l];
    gconst(l >> 4, sA[0], aA[0], bB[0]);
  } else {  // producer: Wih_e1 rows 64j+l, bias folded into xg
#pragma unroll
    for (int j = 0; j < 3; ++j) {
      const int r = 64 * j + l;
      load_row_h2(W0 + (size_t)r * 64, 64, w + j * 32);
      bias[j] = b0i[r] + b0h[r];
    }
    xp = (const float2*)(x + (size_t)b * T * 64) + (l & 31);
    if (l < 32) {
      float2 x0 = xp[0], x1 = xp[32];
      union { h2 h; uint32_t u; } c0, c1;
      c0.h = pk2(x0.x, x0.y);
      c1.h = pk2(x1.x, x1.y);
      xrow16[0][l] = c0.u;
      xrow16[1][l] = c1.u;
      va = xp[64];
      vb = xp[96];
    }
    WAVE_SYNC();
    uint4 xq[8];
    const uint4* xr = (const uint4*)&xrow16[0][0];
#pragma unroll
    for (int i = 0; i < 8; ++i) xq[i] = xr[i];
#pragma unroll
    for (int j = 0; j < 3; ++j) {
      float a0 = bias[j], a1 = 0.f;
      dot2acc<8>(w + j * 32, xq, a0, a1);
      xg1[0][64 * j + l] = a0 + a1;
    }
  }
  BLOCK_SYNC();

  auto estep = [&](int s, int P) {
    const int Q = P ^ 1;
    if (wv == 0) {
      if (s < T) {
        float xgv[4];
#pragma unroll
        for (int j = 0; j < 4; ++j) xgv[j] = xg1[P][j * 48 + uu];
        uint4 hq[6];
        fetch_q<6>(&hb1[Q][0], hq);
        float gv[4];
#pragma unroll
        for (int j = 0; j < 4; ++j) {
          float a0 = xgv[j], a1 = 0.f;
          dot2acc<6>(w + j * 24, hq, a0, a1);
          gv[j] = (j == 2) ? act_tanh(a0 + a1) : act_sig(a0 + a1);
        }
        float h = comb4(gv[0], gv[1], gv[2], gv[3], c);
        if (l < 48) hb1[P][l] = (half_t)h;
      }
    } else if (wv == 1) {
      if (s >= 1 && s <= T) {
        uint4 xv[6], hq[4];
        fetch_q<6>(&hb1[Q][0], xv);
        fetch_q<4>(&hb2[Q][0], hq);
        float gv[2];
#pragma unroll
        for (int j = 0; j < 2; ++j) {
          float a0 = bias[j], a1 = 0.f;
          dot2acc<6>(w + j * 40, xv, a0, a1);
          dot2acc<4>(w + j * 40 + 24, hq, a0, a1);
          gv[j] = act_rt(a0 + a1, sA[j], aA[j], bB[j]);
        }
        float h = pair_combine(gv[0], gv[1], l, c);
        if (l < 32) hb2[P][l & 31] = (half_t)h;
      }
    } else if (wv == 2) {
      if (s >= 2) {  // t = s-2 < T guaranteed by NS
        uint4 xv[4], hq[2];
        fetch_q<4>(&hb2[Q][0], xv);
        fetch_q<2>(&hb3[Q][0], hq);
        float a0 = bias[0], a1 = 0.f;
        dot2acc<4>(w, xv, a0, a1);
        dot2acc<2>(w + 16, hq, a0, a1);
        float gvv = act_rt(a0 + a1, sA[0], aA[0], bB[0]);
        float s1 = __shfl_xor(gvv, 16, 64);
        float r0 = __shfl_xor(gvv, 32, 64);
        float r1 = __shfl_xor(s1, 32, 64);
        float h = comb4(gvv, s1, r0, r1, c);
        if (l < 16) {
          hb3[P][l] = (half_t)h;
          if (s - 2 == T - 1) lat[(size_t)b * 16 + l] = h;
        }
      }
    } else {
      if (s + 2 < T && l < 32) {
        union { h2 h; uint32_t u; } cc2;
        float2 v = P ? vb : va;
        cc2.h = pk2(v.x, v.y);
        xrow16[P][l] = cc2.u;
        if (s + 4 < T) {
          float2 nv = xp[(size_t)(s + 4) * 32];
          if (P) vb = nv; else va = nv;
        }
      }
      if (s + 1 < T) {
        WAVE_SYNC();
        uint4 xq[8];
        const uint4* xr = (const uint4*)&xrow16[Q][0];
#pragma unroll
        for (int i = 0; i < 8; ++i) xq[i] = xr[i];
#pragma unroll
        for (int j = 0; j < 3; ++j) {
          float a0 = bias[j], a1 = 0.f;
          dot2acc<8>(w + j * 32, xq, a0, a1);
          xg1[Q][64 * j + l] = a0 + a1;
        }
      }
    }
    BLOCK_SYNC();
  };

  const int NS = T + 2;  // 514, even
  for (int sb = 0; sb < NS; sb += 2) {
    estep(sb, 0);
    estep(sb + 1, 1);
  }
}

// ===================== Decoder =====================
// 512 blocks x 256 threads.
// wv0 = d1 (pair H=32, latent folded; 32 dots) + xg_d2 GEMM (48 dots, reuses
//       the same hb1[Q] read)                       skew 0 / xg for t-1
// wv1 = d2-rec (unit-per-lane H=48, 96 h-dots)      skew 2
// wv2 = d3 pair units 0-31 (112 dots)               skew 3
// wv3 = d3 pair units 32-63                         skew 3
__global__ __launch_bounds__(256, 2) void dec_ker(
    const float* __restrict__ W3, const float* __restrict__ U3, const float* __restrict__ b3i, const float* __restrict__ b3h,
    const float* __restrict__ W4, const float* __restrict__ U4, const float* __restrict__ b4i, const float* __restrict__ b4h,
    const float* __restrict__ W5, const float* __restrict__ U5, const float* __restrict__ b5i, const float* __restrict__ b5h,
    const float* __restrict__ lat, float* __restrict__ out, int T) {
  __shared__ __align__(16) half_t hb1[2][32];
  __shared__ __align__(16) half_t hb2[2][48];
  __shared__ __align__(16) half_t hb3[2][64];
  __shared__ __align__(16) float xg2[2][192];  // wv0 -> d2 (bias folded)

  const int tid = threadIdx.x, wv = tid >> 6, l = tid & 63, b = blockIdx.x;
  const int uu = (l < 48) ? l : 47;

  if (tid < 32) { hb1[0][tid] = (half_t)0.f; hb1[1][tid] = (half_t)0.f; }
  if (tid < 48) { hb2[0][tid] = (half_t)0.f; hb2[1][tid] = (half_t)0.f; }
  if (tid < 64) { hb3[0][tid] = (half_t)0.f; hb3[1][tid] = (half_t)0.f; }

  h2 w[112];
  float bias[3] = {0.f, 0.f, 0.f};
  float bx[3] = {0.f, 0.f, 0.f};
  float sA[2], aA[2], bB[2];
  float c = 0.f;
  const int u2 = (l & 31) + ((wv == 3) ? 32 : 0);  // d3 unit

  if (wv == 0) {  // d1 + xg_d2
    const int u = l & 31, g0 = (l < 32) ? 0 : 2;
    const float* lt = lat + (size_t)b * 16;
#pragma unroll
    for (int j = 0; j < 2; ++j) {
      const int r = (g0 + j) * 32 + u;
      load_row_h2(U3 + (size_t)r * 32, 32, w + j * 16);
      float s0 = b3i[r] + b3h[r];
      const float* wr = W3 + (size_t)r * 16;
#pragma unroll
      for (int d = 0; d < 16; ++d) s0 = fmaf(wr[d], lt[d], s0);
      bias[j] = s0;
      gconst(g0 + j, sA[j], aA[j], bB[j]);
    }
#pragma unroll
    for (int jj = 0; jj < 3; ++jj) {  // Wih_d2 rows 64jj+l (x-part GEMM)
      const int r = 64 * jj + l;
      load_row_h2(W4 + (size_t)r * 32, 32, w + 32 + jj * 16);
      bx[jj] = b4i[r] + b4h[r];
    }
  } else if (wv == 1) {  // d2-rec: rows j*48+uu of Whh only
#pragma unroll
    for (int j = 0; j < 4; ++j)
      load_row_h2(U4 + (size_t)(j * 48 + uu) * 48, 48, w + j * 24);
  } else {  // d3 pair halves
    const int g0 = (l < 32) ? 0 : 2;
#pragma unroll
    for (int j = 0; j < 2; ++j) {
      const int r = (g0 + j) * 64 + u2;
      load_row_h2(W5 + (size_t)r * 48, 48, w + j * 56);
      load_row_h2(U5 + (size_t)r * 64, 64, w + j * 56 + 24);
      bias[j] = b5i[r] + b5h[r];
      gconst(g0 + j, sA[j], aA[j], bB[j]);
    }
  }
  BLOCK_SYNC();

  auto dstep = [&](int s, int P) {
    const int Q = P ^ 1;
    if (wv == 0) {
      if (s <= T) {
        uint4 hq[4];
        fetch_q<4>(&hb1[Q][0], hq);
        if (s < T) {
          float gv[2];
#pragma unroll
          for (int j = 0; j < 2; ++j) {
            float a0 = bias[j], a1 = 0.f;
            dot2acc<4>(w + j * 16, hq, a0, a1);
            gv[j] = act_rt(a0 + a1, sA[j], aA[j], bB[j]);
          }
          float h = pair_combine(gv[0], gv[1], l, c);
          if (l < 32) hb1[P][l & 31] = (half_t)h;
        }
        if (s >= 1) {  // xg_d2 for t' = s-1 from the same hq
#pragma unroll
          for (int jj = 0; jj < 3; ++jj) {
            float a0 = bx[jj], a1 = 0.f;
            dot2acc<4>(w + 32 + jj * 16, hq, a0, a1);
            xg2[P][64 * jj + l] = a0 + a1;
          }
        }
      }
    } else if (wv == 1) {
      if (s >= 2 && s < T + 2) {
        float xgv[4];
#pragma unroll
        for (int j = 0; j < 4; ++j) xgv[j] = xg2[Q][j * 48 + uu];
        uint4 hq[6];
        fetch_q<6>(&hb2[Q][0], hq);
        float gv[4];
#pragma unroll
        for (int j = 0; j < 4; ++j) {
          float a0 = xgv[j], a1 = 0.f;
          dot2acc<6>(w + j * 24, hq, a0, a1);
          gv[j] = (j == 2) ? act_tanh(a0 + a1) : act_sig(a0 + a1);
        }
        float h = comb4(gv[0], gv[1], gv[2], gv[3], c);
        if (l < 48) hb2[P][l] = (half_t)h;
      }
    } else {
      if (s >= 3) {  // t = s-3 < T guaranteed by NS guards below
        const int t = s - 3;
        if (t < T) {
          uint4 xv[6], hq[8];
          fetch_q<6>(&hb2[Q][0], xv);
          fetch_q<8>(&hb3[Q][0], hq);
          float gv[2];
#pragma unroll
          for (int j = 0; j < 2; ++j) {
            float a0 = bias[j], a1 = 0.f;
            dot2acc<6>(w + j * 56, xv, a0, a1);
            dot2acc<8>(w + j * 56 + 24, hq, a0, a1);
            gv[j] = act_rt(a0 + a1, sA[j], aA[j], bB[j]);
          }
          float h = pair_combine(gv[0], gv[1], l, c);
          if (l < 32) {
            hb3[P][u2] = (half_t)h;
            out[((size_t)b * T + t) * 64 + u2] = h;
          }
        }
      }
    }
    BLOCK_SYNC();
  };

  const int NS = T + 4;  // 516, even; s=T+3 fully idle
  for (int sb = 0; sb < NS; sb += 2) {
    dstep(sb, 0);
    dstep(sb + 1, 1);
  }
}

extern "C" void kernel_launch(void* const* d_in, const int* in_sizes, int n_in,
                              void* d_out, int out_size, void* d_ws, size_t ws_size,
                              hipStream_t stream) {
  (void)in_sizes; (void)n_in; (void)out_size; (void)ws_size;
  const float* x = (const float*)d_in[0];
  const float *W[6], *U[6], *Bi[6], *Bh[6];
  for (int lyr = 0; lyr < 6; ++lyr) {
    W[lyr]  = (const float*)d_in[1 + 4 * lyr + 0];
    U[lyr]  = (const float*)d_in[1 + 4 * lyr + 1];
    Bi[lyr] = (const float*)d_in[1 + 4 * lyr + 2];
    Bh[lyr] = (const float*)d_in[1 + 4 * lyr + 3];
  }
  float* out = (float*)d_out;
  const int T = 512;
  float* lat = (float*)d_ws;  // 32 KB

  enc_ker<<<dim3(512), dim3(256), 0, stream>>>(
      W[0], U[0], Bi[0], Bh[0], W[1], U[1], Bi[1], Bh[1], W[2], U[2], Bi[2], Bh[2],
      x, lat, T);
  dec_ker<<<dim3(512), dim3(256), 0, stream>>>(
      W[3], U[3], Bi[3], Bh[3], W[4], U[4], Bi[4], Bh[4], W[5], U[5], Bi[5], Bh[5],
      lat, out, T);
}

// Round 8
// 723.714 us; speedup vs baseline: 3.6064x; 1.0942x over previous
//
#include <hip/hip_runtime.h>
#include <hip/hip_bf16.h>
#include <cstdint>
#include <cstddef>

typedef _Float16 half_t;
typedef decltype(__builtin_amdgcn_cvt_pkrtz(0.f, 0.f)) h2;  // v2f16

__device__ __forceinline__ h2 pk2(float a, float b) { return __builtin_amdgcn_cvt_pkrtz(a, b); }
__device__ __forceinline__ float fdot2f(h2 a, h2 b, float c) { return __builtin_amdgcn_fdot2(a, b, c, false); }
__device__ __forceinline__ h2 u2h(uint32_t u) { union { uint32_t u; h2 h; } v; v.u = u; return v.h; }

#define WAVE_SYNC() asm volatile("s_waitcnt lgkmcnt(0)" ::: "memory")
// Block barrier WITHOUT vmcnt drain: global loads stay in flight.
#define BLOCK_SYNC()                                   \
  do {                                                 \
    asm volatile("s_waitcnt lgkmcnt(0)" ::: "memory"); \
    __builtin_amdgcn_s_barrier();                      \
    asm volatile("" ::: "memory");                     \
  } while (0)

template <int NQ>
__device__ __forceinline__ void fetch_q(const half_t* hb, uint4* q) {
  const uint4* p = (const uint4*)hb;
#pragma unroll
  for (int i = 0; i < NQ; ++i) q[i] = p[i];
}

// 8 f16-MACs per uint4, FOUR independent accumulator chains.
template <int NQ>
__device__ __forceinline__ void dot4(const h2* w, const uint4* q, float* a) {
#pragma unroll
  for (int i = 0; i < NQ; ++i) {
    a[0] = fdot2f(w[4 * i + 0], u2h(q[i].x), a[0]);
    a[1] = fdot2f(w[4 * i + 1], u2h(q[i].y), a[1]);
    a[2] = fdot2f(w[4 * i + 2], u2h(q[i].z), a[2]);
    a[3] = fdot2f(w[4 * i + 3], u2h(q[i].w), a[3]);
  }
}

__device__ __forceinline__ void load_row_h2(const float* src, int nf, h2* dst) {
  const float2* s2 = (const float2*)src;
  for (int p = 0; p < nf / 2; ++p) { float2 v = s2[p]; dst[p] = pk2(v.x, v.y); }
}

__device__ __forceinline__ void gconst(int gt, float& s, float& a, float& b) {
  const bool isT = (gt == 2);
  s = isT ? -2.88539008f : -1.44269504f;
  a = isT ? 2.f : 1.f;
  b = isT ? -1.f : 0.f;
}

__device__ __forceinline__ float act_sig(float x) {
  float e = exp2f(-1.44269504f * x);
  return __builtin_amdgcn_rcpf(1.f + e);
}
__device__ __forceinline__ float act_tanh(float x) {
  float e = exp2f(-2.88539008f * x);
  return fmaf(2.f, __builtin_amdgcn_rcpf(1.f + e), -1.f);
}
__device__ __forceinline__ float act_rt(float x, float s, float a, float b) {
  float e = exp2f(s * x);
  return fmaf(a, __builtin_amdgcn_rcpf(1.f + e), b);
}

__device__ __forceinline__ float comb4(float gi, float gf, float gg, float go, float& c) {
  c = fmaf(gf, c, gi * gg);
  float e2 = exp2f(-2.88539008f * c);
  return go * fmaf(2.f, __builtin_amdgcn_rcpf(1.f + e2), -1.f);
}

// Pair layers (pow2 H): lane l<32 computed gates (i,f), lane l+32 (g,o) of the
// same unit. One shfl_xor(32) pair completes the set.
__device__ __forceinline__ float pair_combine(float gv0, float gv1, int l, float& c) {
  float sw0 = __shfl_xor(gv0, 32, 64);
  float sw1 = __shfl_xor(gv1, 32, 64);
  const bool lo = (l < 32);
  float gi = lo ? gv0 : sw0, gf = lo ? gv1 : sw1;
  float gg = lo ? sw0 : gv0, go = lo ? sw1 : gv1;
  return comb4(gi, gf, gg, go, c);
}

// ===================== Fused autoencoder =====================
// 512 blocks x 256 threads, one block per batch chain, enc phase then dec phase.
// Enc: wv0=e1-rec(96d) wv1=e2 pair(80d) wv2=e3(24d) wv3=producer(x+e1-xGEMM)
// Dec: wv0=d1+xg_d2(80d) wv1=d2-rec(96d) wv2,3=d3 pair halves(112d)
__global__ __launch_bounds__(256, 2) void ae_ker(
    const float* __restrict__ W0, const float* __restrict__ U0, const float* __restrict__ b0i, const float* __restrict__ b0h,
    const float* __restrict__ W1, const float* __restrict__ U1, const float* __restrict__ b1i, const float* __restrict__ b1h,
    const float* __restrict__ W2, const float* __restrict__ U2, const float* __restrict__ b2i, const float* __restrict__ b2h,
    const float* __restrict__ W3, const float* __restrict__ U3, const float* __restrict__ b3i, const float* __restrict__ b3h,
    const float* __restrict__ W4, const float* __restrict__ U4, const float* __restrict__ b4i, const float* __restrict__ b4h,
    const float* __restrict__ W5, const float* __restrict__ U5, const float* __restrict__ b5i, const float* __restrict__ b5h,
    const float* __restrict__ x, float* __restrict__ out, int T) {
  __shared__ __align__(16) half_t hb1e[2][48];
  __shared__ __align__(16) half_t hb2e[2][32];
  __shared__ __align__(16) half_t hb3e[2][16];
  __shared__ __align__(16) uint32_t xrow16[2][32];
  __shared__ __align__(16) float xg1[2][192];
  __shared__ __align__(16) float latb[16];
  __shared__ __align__(16) half_t hb1d[2][32];
  __shared__ __align__(16) half_t hb2d[2][48];
  __shared__ __align__(16) half_t hb3d[2][64];
  __shared__ __align__(16) float xg2[2][192];

  const int tid = threadIdx.x, wv = tid >> 6, l = tid & 63, b = blockIdx.x;
  const int uu = (l < 48) ? l : 47;

  if (tid < 48) { hb1e[0][tid] = (half_t)0.f; hb1e[1][tid] = (half_t)0.f; }
  if (tid < 32) { hb2e[0][tid] = (half_t)0.f; hb2e[1][tid] = (half_t)0.f; }
  if (tid < 16) { hb3e[0][tid] = (half_t)0.f; hb3e[1][tid] = (half_t)0.f; }

  h2 w[112];
  float bias[3] = {0.f, 0.f, 0.f};
  float bx[3] = {0.f, 0.f, 0.f};
  float sA[2], aA[2], bB[2];
  float c = 0.f;
  float2 va = {0.f, 0.f}, vb = {0.f, 0.f};
  const float2* xp = nullptr;

  // ---------------- encoder weight load ----------------
  if (wv == 0) {  // e1-rec: unit-per-lane, Whh rows j*48+uu
#pragma unroll
    for (int j = 0; j < 4; ++j)
      load_row_h2(U0 + (size_t)(j * 48 + uu) * 48, 48, w + j * 24);
  } else if (wv == 1) {  // e2 pair
    const int u = l & 31, g0 = (l < 32) ? 0 : 2;
#pragma unroll
    for (int j = 0; j < 2; ++j) {
      const int r = (g0 + j) * 32 + u;
      load_row_h2(W1 + (size_t)r * 48, 48, w + j * 40);
      load_row_h2(U1 + (size_t)r * 32, 32, w + j * 40 + 24);
      bias[j] = b1i[r] + b1h[r];
      gconst(g0 + j, sA[j], aA[j], bB[j]);
    }
  } else if (wv == 2) {  // e3: row r=l
    load_row_h2(W2 + (size_t)l * 32, 32, w);
    load_row_h2(U2 + (size_t)l * 16, 16, w + 16);
    bias[0] = b2i[l] + b2h[l];
    gconst(l >> 4, sA[0], aA[0], bB[0]);
  } else {  // producer: Wih_e1 rows 64j+l
#pragma unroll
    for (int j = 0; j < 3; ++j) {
      const int r = 64 * j + l;
      load_row_h2(W0 + (size_t)r * 64, 64, w + j * 32);
      bias[j] = b0i[r] + b0h[r];
    }
    xp = (const float2*)(x + (size_t)b * T * 64) + (l & 31);
    if (l < 32) {
      float2 x0 = xp[0], x1 = xp[32];
      union { h2 h; uint32_t u; } c0, c1;
      c0.h = pk2(x0.x, x0.y);
      c1.h = pk2(x1.x, x1.y);
      xrow16[0][l] = c0.u;
      xrow16[1][l] = c1.u;
      va = xp[64];
      vb = xp[96];
    }
    WAVE_SYNC();
    uint4 xq[8];
    const uint4* xr = (const uint4*)&xrow16[0][0];
#pragma unroll
    for (int i = 0; i < 8; ++i) xq[i] = xr[i];
#pragma unroll
    for (int j = 0; j < 3; ++j) {
      float a[4] = {bias[j], 0.f, 0.f, 0.f};
      dot4<8>(w + j * 32, xq, a);
      xg1[0][64 * j + l] = (a[0] + a[1]) + (a[2] + a[3]);
    }
  }
  BLOCK_SYNC();

  // ---------------- encoder loop ----------------
  auto estep = [&](const bool G, int s, int P) {
    const int Q = P ^ 1;
    if (wv == 0) {
      if (!G || s < T) {
        float xgv[4];
#pragma unroll
        for (int j = 0; j < 4; ++j) xgv[j] = xg1[P][j * 48 + uu];
        uint4 hq[6];
        fetch_q<6>(&hb1e[Q][0], hq);
        __builtin_amdgcn_s_setprio(1);
        float gv[4];
#pragma unroll
        for (int j = 0; j < 4; ++j) {
          float a[4] = {xgv[j], 0.f, 0.f, 0.f};
          dot4<6>(w + j * 24, hq, a);
          float pre = (a[0] + a[1]) + (a[2] + a[3]);
          gv[j] = (j == 2) ? act_tanh(pre) : act_sig(pre);
        }
        __builtin_amdgcn_s_setprio(0);
        float h = comb4(gv[0], gv[1], gv[2], gv[3], c);
        if (l < 48) hb1e[P][l] = (half_t)h;
      }
    } else if (wv == 1) {
      if (!G || (s >= 1 && s <= T)) {
        uint4 xv[6], hq[4];
        fetch_q<6>(&hb1e[Q][0], xv);
        fetch_q<4>(&hb2e[Q][0], hq);
        float gv[2];
#pragma unroll
        for (int j = 0; j < 2; ++j) {
          float a[4] = {bias[j], 0.f, 0.f, 0.f};
          dot4<6>(w + j * 40, xv, a);
          dot4<4>(w + j * 40 + 24, hq, a);
          gv[j] = act_rt((a[0] + a[1]) + (a[2] + a[3]), sA[j], aA[j], bB[j]);
        }
        float h = pair_combine(gv[0], gv[1], l, c);
        if (l < 32) hb2e[P][l & 31] = (half_t)h;
      }
    } else if (wv == 2) {
      if (!G || s >= 2) {
        uint4 xv[4], hq[2];
        fetch_q<4>(&hb2e[Q][0], xv);
        fetch_q<2>(&hb3e[Q][0], hq);
        float a[4] = {bias[0], 0.f, 0.f, 0.f};
        dot4<4>(w, xv, a);
        dot4<2>(w + 16, hq, a);
        float gvv = act_rt((a[0] + a[1]) + (a[2] + a[3]), sA[0], aA[0], bB[0]);
        float s1 = __shfl_xor(gvv, 16, 64);
        float r0 = __shfl_xor(gvv, 32, 64);
        float r1 = __shfl_xor(s1, 32, 64);
        float h = comb4(gvv, s1, r0, r1, c);
        if (l < 16) {
          hb3e[P][l] = (half_t)h;
          if (G && s - 2 == T - 1) latb[l] = h;  // only reachable in epilogue
        }
      }
    } else {
      if ((!G || s + 2 < T) && l < 32) {
        union { h2 h; uint32_t u; } cc2;
        float2 v = P ? vb : va;
        cc2.h = pk2(v.x, v.y);
        xrow16[P][l] = cc2.u;
        if (!G || s + 4 < T) {
          float2 nv = xp[(size_t)(s + 4) * 32];
          if (P) vb = nv; else va = nv;
        }
      }
      if (!G || s + 1 < T) {
        WAVE_SYNC();
        uint4 xq[8];
        const uint4* xr = (const uint4*)&xrow16[Q][0];
#pragma unroll
        for (int i = 0; i < 8; ++i) xq[i] = xr[i];
        __builtin_amdgcn_s_setprio(1);
#pragma unroll
        for (int j = 0; j < 3; ++j) {
          float a[4] = {bias[j], 0.f, 0.f, 0.f};
          dot4<8>(w + j * 32, xq, a);
          xg1[Q][64 * j + l] = (a[0] + a[1]) + (a[2] + a[3]);
        }
        __builtin_amdgcn_s_setprio(0);
      }
    }
    BLOCK_SYNC();
  };

  {
    const int NS = T + 2;  // 514
    for (int s = 0; s < 4; ++s) estep(true, s, s & 1);
    for (int s = 4; s < 508; s += 2) { estep(false, s, 0); estep(false, s + 1, 1); }
    for (int s = 508; s < NS; ++s) estep(true, s, s & 1);
  }

  // ---------------- phase switch: decoder weights ----------------
  c = 0.f;
  if (tid < 32) { hb1d[0][tid] = (half_t)0.f; hb1d[1][tid] = (half_t)0.f; }
  if (tid < 48) { hb2d[0][tid] = (half_t)0.f; hb2d[1][tid] = (half_t)0.f; }
  if (tid < 64) { hb3d[0][tid] = (half_t)0.f; hb3d[1][tid] = (half_t)0.f; }
  const int u2 = (l & 31) + ((wv == 3) ? 32 : 0);  // d3 unit

  if (wv == 0) {  // d1 pair (latent folded from LDS) + xg_d2 rows
    const int u = l & 31, g0 = (l < 32) ? 0 : 2;
#pragma unroll
    for (int j = 0; j < 2; ++j) {
      const int r = (g0 + j) * 32 + u;
      load_row_h2(U3 + (size_t)r * 32, 32, w + j * 16);
      float s0 = b3i[r] + b3h[r];
      const float* wr = W3 + (size_t)r * 16;
#pragma unroll
      for (int d = 0; d < 16; ++d) s0 = fmaf(wr[d], latb[d], s0);
      bias[j] = s0;
      gconst(g0 + j, sA[j], aA[j], bB[j]);
    }
#pragma unroll
    for (int jj = 0; jj < 3; ++jj) {
      const int r = 64 * jj + l;
      load_row_h2(W4 + (size_t)r * 32, 32, w + 32 + jj * 16);
      bx[jj] = b4i[r] + b4h[r];
    }
  } else if (wv == 1) {  // d2-rec unit-per-lane
#pragma unroll
    for (int j = 0; j < 4; ++j)
      load_row_h2(U4 + (size_t)(j * 48 + uu) * 48, 48, w + j * 24);
  } else {  // d3 pair halves
    const int g0 = (l < 32) ? 0 : 2;
#pragma unroll
    for (int j = 0; j < 2; ++j) {
      const int r = (g0 + j) * 64 + u2;
      load_row_h2(W5 + (size_t)r * 48, 48, w + j * 56);
      load_row_h2(U5 + (size_t)r * 64, 64, w + j * 56 + 24);
      bias[j] = b5i[r] + b5h[r];
      gconst(g0 + j, sA[j], aA[j], bB[j]);
    }
  }
  BLOCK_SYNC();

  // ---------------- decoder loop ----------------
  auto dstep = [&](const bool G, int s, int P) {
    const int Q = P ^ 1;
    if (wv == 0) {
      if (!G || s <= T) {
        uint4 hq[4];
        fetch_q<4>(&hb1d[Q][0], hq);
        if (!G || s < T) {
          float gv[2];
#pragma unroll
          for (int j = 0; j < 2; ++j) {
            float a[4] = {bias[j], 0.f, 0.f, 0.f};
            dot4<4>(w + j * 16, hq, a);
            gv[j] = act_rt((a[0] + a[1]) + (a[2] + a[3]), sA[j], aA[j], bB[j]);
          }
          float h = pair_combine(gv[0], gv[1], l, c);
          if (l < 32) hb1d[P][l & 31] = (half_t)h;
        }
        if (!G || s >= 1) {
#pragma unroll
          for (int jj = 0; jj < 3; ++jj) {
            float a[4] = {bx[jj], 0.f, 0.f, 0.f};
            dot4<4>(w + 32 + jj * 16, hq, a);
            xg2[P][64 * jj + l] = (a[0] + a[1]) + (a[2] + a[3]);
          }
        }
      }
    } else if (wv == 1) {
      if (!G || (s >= 2 && s < T + 2)) {
        float xgv[4];
#pragma unroll
        for (int j = 0; j < 4; ++j) xgv[j] = xg2[Q][j * 48 + uu];
        uint4 hq[6];
        fetch_q<6>(&hb2d[Q][0], hq);
        __builtin_amdgcn_s_setprio(1);
        float gv[4];
#pragma unroll
        for (int j = 0; j < 4; ++j) {
          float a[4] = {xgv[j], 0.f, 0.f, 0.f};
          dot4<6>(w + j * 24, hq, a);
          float pre = (a[0] + a[1]) + (a[2] + a[3]);
          gv[j] = (j == 2) ? act_tanh(pre) : act_sig(pre);
        }
        __builtin_amdgcn_s_setprio(0);
        float h = comb4(gv[0], gv[1], gv[2], gv[3], c);
        if (l < 48) hb2d[P][l] = (half_t)h;
      }
    } else {
      if (!G || (s >= 3 && s < T + 3)) {
        uint4 xv[6], hq[8];
        fetch_q<6>(&hb2d[Q][0], xv);
        fetch_q<8>(&hb3d[Q][0], hq);
        __builtin_amdgcn_s_setprio(1);
        float gv[2];
#pragma unroll
        for (int j = 0; j < 2; ++j) {
          float a[4] = {bias[j], 0.f, 0.f, 0.f};
          dot4<6>(w + j * 56, xv, a);
          dot4<8>(w + j * 56 + 24, hq, a);
          gv[j] = act_rt((a[0] + a[1]) + (a[2] + a[3]), sA[j], aA[j], bB[j]);
        }
        __builtin_amdgcn_s_setprio(0);
        float h = pair_combine(gv[0], gv[1], l, c);
        if (l < 32) {
          hb3d[P][u2] = (half_t)h;
          out[((size_t)b * T + (s - 3)) * 64 + u2] = h;
        }
      }
    }
    BLOCK_SYNC();
  };

  {
    const int NS = T + 4;  // 516
    for (int s = 0; s < 4; ++s) dstep(true, s, s & 1);
    for (int s = 4; s < 508; s += 2) { dstep(false, s, 0); dstep(false, s + 1, 1); }
    for (int s = 508; s < NS; ++s) dstep(true, s, s & 1);
  }
}

extern "C" void kernel_launch(void* const* d_in, const int* in_sizes, int n_in,
                              void* d_out, int out_size, void* d_ws, size_t ws_size,
                              hipStream_t stream) {
  (void)in_sizes; (void)n_in; (void)out_size; (void)d_ws; (void)ws_size;
  const float* x = (const float*)d_in[0];
  const float *W[6], *U[6], *Bi[6], *Bh[6];
  for (int lyr = 0; lyr < 6; ++lyr) {
    W[lyr]  = (const float*)d_in[1 + 4 * lyr + 0];
    U[lyr]  = (const float*)d_in[1 + 4 * lyr + 1];
    Bi[lyr] = (const float*)d_in[1 + 4 * lyr + 2];
    Bh[lyr] = (const float*)d_in[1 + 4 * lyr + 3];
  }
  float* out = (float*)d_out;
  const int T = 512;

  ae_ker<<<dim3(512), dim3(256), 0, stream>>>(
      W[0], U[0], Bi[0], Bh[0], W[1], U[1], Bi[1], Bh[1], W[2], U[2], Bi[2], Bh[2],
      W[3], U[3], Bi[3], Bh[3], W[4], U[4], Bi[4], Bh[4], W[5], U[5], Bi[5], Bh[5],
      x, out, T);
}